// Round 1
// 810.722 us; speedup vs baseline: 3.5297x; 3.5297x over previous
//
#include <hip/hip_runtime.h>
#include <stdint.h>

typedef unsigned int uint32;
typedef __attribute__((ext_vector_type(4))) float f32x4;
typedef __attribute__((ext_vector_type(4))) uint32 u32x4;
typedef __attribute__((ext_vector_type(8))) short bf16x8;

// Problem constants
#define NPOS_TOTAL 65536   // B*N = 4*16384
#define WPB 4              // waves per block
#define POS_PER_WAVE 32
#define NBLOCKS 512        // 512*4*32 = 65536 positions
#define CSTRIDE 262144     // 16384*16 floats per channel plane

// ---------------- ws layout (dword offsets) ----------------
// Fragment tables for mfma_f32_16x16x32_bf16.
// A-frag: lane l holds A[row=l&15][k=(l>>4)*8+j], j=0..7, dword r = k-pair (2r,2r+1)
// B-frag: lane l holds B[k=(l>>4)*8+j][col=l&15], same dword packing
// C/D   : lane l holds D[row=(l>>4)*4+r][col=l&15]  (m89/m91-verified)
#define OFF_AW0 0          // [mt*2+s][lane][r] A-frags of W0 (o=mt*16+(l&15), c=s*32+8g+2r)   4096
#define OFF_W2N 4096       // [nt*4+s][lane][r] B-frags of -W2^T (c=nt*16+(l&15), o=s*32+8g+2r) 4096
#define OFF_W3 8192        // [nt*4+s][lane][r] B-frags of +W3^T                                 4096
#define OFF_PW1 12288      // [nt][lane][r]     B-frags of pw1^T (K=8 padded to 32)              1024
#define OFF_PW2 13312      // [nt*2+s][lane][r] B-frags of pw2^T                                 2048
#define N_LDS_TAB 15360    // dwords staged to LDS (60 KB)
#define OFF_CW1 15360      // [(j*2+h)][lane][rr] cw1 gather table, elem e=nt*4+r <-> (c,k)      4096
#define OFF_W1 19456       // [nt*4+s][lane][r] B-frags of +W1^T (global-read)                   4096
#define OFF_CW2 23552      // [j][l2] pack(cw2[l2][j], cw2[l2+64][j])                            512
#define OFF_WOUT 24064     // [c][o2] pack(wout[o2][c], wout[o2+64][c])                          4096
// total 28160 dwords = 112.6 KB of workspace

__device__ __forceinline__ uint32 pack_bf16(float lo, float hi) {
  uint32 a = __builtin_bit_cast(uint32, lo);
  uint32 b = __builtin_bit_cast(uint32, hi);
  return ((b + 0x8000u) & 0xffff0000u) | ((a + 0x8000u) >> 16);
}
__device__ __forceinline__ float bf_lo(uint32 u) { return __builtin_bit_cast(float, u << 16); }
__device__ __forceinline__ float bf_hi(uint32 u) { return __builtin_bit_cast(float, u & 0xffff0000u); }
__device__ __forceinline__ float bcast(float v, int l) {
  return __builtin_bit_cast(float, __builtin_amdgcn_readlane(__builtin_bit_cast(int, v), l));
}
__device__ __forceinline__ uint32 cvt_pk(float lo, float hi) {
  uint32 r;
  asm("v_cvt_pk_bf16_f32 %0, %1, %2" : "=v"(r) : "v"(lo), "v"(hi));
  return r;
}
__device__ __forceinline__ uint32 bperm(int addr, uint32 src) {
  return (uint32)__builtin_amdgcn_ds_bpermute(addr, (int)src);
}
__device__ __forceinline__ float bpermf(int addr, float src) {
  return __builtin_bit_cast(float,
      __builtin_amdgcn_ds_bpermute(addr, __builtin_bit_cast(int, src)));
}
__device__ __forceinline__ f32x4 mfma16(u32x4 a, u32x4 b, f32x4 c) {
  return __builtin_amdgcn_mfma_f32_16x16x32_bf16(
      __builtin_bit_cast(bf16x8, a), __builtin_bit_cast(bf16x8, b), c, 0, 0, 0);
}
__device__ __forceinline__ f32x4 relu4(f32x4 v) {
  f32x4 r;
  r[0] = fmaxf(v[0], 0.f);
  r[1] = fmaxf(v[1], 0.f);
  r[2] = fmaxf(v[2], 0.f);
  r[3] = fmaxf(v[3], 0.f);
  return r;
}

__global__ void pack_weights_kernel(const float* __restrict__ w0, const float* __restrict__ w1,
                                    const float* __restrict__ w2, const float* __restrict__ w3,
                                    const float* __restrict__ pw1, const float* __restrict__ pw2,
                                    const float* __restrict__ cw1, const float* __restrict__ cw2,
                                    const float* __restrict__ wout, uint32* __restrict__ ws) {
  int t = threadIdx.x + blockIdx.x * blockDim.x;
  int stride = blockDim.x * gridDim.x;

  // W0 A-frags: o = mt*16 + (l&15), c = s*32 + (l>>4)*8 + 2r   (w0: [128][64])
  for (int i = t; i < 4096; i += stride) {
    int r = i & 3, l = (i >> 2) & 63, ts = i >> 8;
    int mt = ts >> 1, s = ts & 1;
    int o = mt * 16 + (l & 15);
    int c = s * 32 + ((l >> 4) << 3) + 2 * r;
    ws[OFF_AW0 + i] = pack_bf16(w0[o * 64 + c], w0[o * 64 + c + 1]);
  }
  // -W2^T / +W3^T / +W1^T B-frags: c = nt*16+(l&15), o = s*32+(l>>4)*8+2r  (w[64][128])
  for (int i = t; i < 4096; i += stride) {
    int r = i & 3, l = (i >> 2) & 63, ts = i >> 8;
    int nt = ts >> 2, s = ts & 3;
    int c = nt * 16 + (l & 15);
    int o = s * 32 + ((l >> 4) << 3) + 2 * r;
    ws[OFF_W2N + i] = pack_bf16(-w2[c * 128 + o], -w2[c * 128 + o + 1]);
    ws[OFF_W3 + i] = pack_bf16(w3[c * 128 + o], w3[c * 128 + o + 1]);
    ws[OFF_W1 + i] = pack_bf16(w1[c * 128 + o], w1[c * 128 + o + 1]);
  }
  // pw1^T B-frags (K=8 zero-padded to 32): m = nt*16+(l&15), q = (l>>4)*8+2r  (pw1: [64][8])
  for (int i = t; i < 1024; i += stride) {
    int r = i & 3, l = (i >> 2) & 63, nt = i >> 8;
    int m = nt * 16 + (l & 15);
    int qq = ((l >> 4) << 3) + 2 * r;
    float lo = (qq < 8) ? pw1[m * 8 + qq] : 0.f;
    float hi = (qq < 8) ? pw1[m * 8 + qq + 1] : 0.f;
    ws[OFF_PW1 + i] = pack_bf16(lo, hi);
  }
  // pw2^T B-frags: m2 = nt*16+(l&15), m = s*32+(l>>4)*8+2r   (pw2: [64][64])
  for (int i = t; i < 2048; i += stride) {
    int r = i & 3, l = (i >> 2) & 63, ts = i >> 8;
    int nt = ts >> 1, s = ts & 1;
    int m2 = nt * 16 + (l & 15);
    int m = s * 32 + ((l >> 4) << 3) + 2 * r;
    ws[OFF_PW2 + i] = pack_bf16(pw2[m2 * 64 + m], pw2[m2 * 64 + m + 1]);
  }
  // cw1 gather table for phase F (matches transposed D layout: elem e = nt*4+r
  //   <-> c = nt*16+(l&15), k = 4*(l>>4)+r), dword d = h*4+rr packs elems 2d,2d+1
  for (int i = t; i < 4096; i += stride) {
    int rr = i & 3, l = (i >> 2) & 63, th = i >> 8;  // th = j*2+h
    int j = th >> 1, h = th & 1;
    int d = h * 4 + rr;
    int qq = l & 15, gg = l >> 4;
    int e0 = 2 * d, e1 = 2 * d + 1;
    int c0 = (e0 >> 2) * 16 + qq, k0 = gg * 4 + (e0 & 3);
    int c1 = (e1 >> 2) * 16 + qq, k1 = gg * 4 + (e1 & 3);
    ws[OFF_CW1 + i] = pack_bf16(cw1[j * 1024 + c0 * 16 + k0], cw1[j * 1024 + c1 * 16 + k1]);
  }
  // cw2 packed (as before)
  for (int i = t; i < 512; i += stride) {
    int j = i >> 6, l2 = i & 63;
    ws[OFF_CW2 + i] = pack_bf16(cw2[l2 * 8 + j], cw2[(l2 + 64) * 8 + j]);
  }
  // wout packed (as before)
  for (int i = t; i < 4096; i += stride) {
    int c = i >> 6, o2 = i & 63;
    ws[OFF_WOUT + i] = pack_bf16(wout[o2 * 64 + c], wout[(o2 + 64) * 64 + c]);
  }
}

__launch_bounds__(256, 2)
__global__ void pt_mfma(const float* __restrict__ feats, const float* __restrict__ ppfs,
                        const float* __restrict__ b0, const float* __restrict__ b1,
                        const float* __restrict__ b2, const float* __restrict__ b3,
                        const float* __restrict__ cb2, const float* __restrict__ bout,
                        const uint32* __restrict__ ws, float* __restrict__ out) {
  __shared__ uint32 sT[N_LDS_TAB];     // 60 KB fragment tables
  __shared__ float sId[WPB][128];      // per-wave identity column xn[:,0] (fp32, exact)

  const int tid = threadIdx.x;
  {
    u32x4* dst = (u32x4*)sT;
    const u32x4* src = (const u32x4*)ws;
#pragma unroll 1
    for (int i = tid; i < N_LDS_TAB / 4; i += 256) dst[i] = src[i];
  }
  __syncthreads();

  const int lane = tid & 63;
  const int wv = tid >> 6;
  const int q = lane & 15;   // fragment column (N index)
  const int g = lane >> 4;   // fragment group
  const bool isLo = (lane < 32);
  const bool qlo = ((q & 4) == 0);

  // bpermute byte addresses for C/D-layout -> A-frag conversion:
  // dest (g,q) dword t pulls from lane q + 16*((2g + (t>>1)) & 3)
  const int addrLo = 4 * (q + 16 * ((2 * g) & 3));
  const int addrHi = 4 * (q + 16 * ((2 * g + 1) & 3));
  const int addrC0 = 4 * (16 * g);                    // column-0 broadcast source
  const int addrI0 = 4 * ((q & 3) * 16 + 4 * g);      // softmax gather base

  // biases
  f32x4 b0f[8];
#pragma unroll
  for (int mt = 0; mt < 8; mt++) b0f[mt] = *(const f32x4*)(b0 + mt * 16 + 4 * g);
  float bfsF[4], b3F[4];
#pragma unroll
  for (int nt = 0; nt < 4; nt++) {
    bfsF[nt] = b1[nt * 16 + q] - b2[nt * 16 + q];
    b3F[nt] = b3[nt * 16 + q];
  }
  const float cb2A = cb2[lane], cb2B = cb2[lane + 64];
  const float boutA = bout[lane], boutB = bout[lane + 64];

  float* idp = &sId[wv][0];

  const int wgid = blockIdx.x * WPB + wv;
  const int p0 = wgid * POS_PER_WAVE;

  int zoff = 0;  // opaque zero: defeats LICM hoisting of table loads (register blow-up)

#pragma unroll 1
  for (int pi = 0; pi < POS_PER_WAVE; ++pi) {
    asm volatile("" : "+v"(zoff));
    const int p = p0 + pi;
    const int b = p >> 14, npos = p & 16383;

    const u32x4* gcw1_4 = (const u32x4*)(ws + OFF_CW1) + zoff;
    const u32x4* gw1_4 = (const u32x4*)(ws + OFF_W1) + zoff;
    const uint32* gcw2p = ws + OFF_CW2 + zoff;
    const uint32* gwoutp = ws + OFF_WOUT + zoff;

    // ---- F B-frags: fB[s] dword t = pack(F[c][q], F[c+1][q]), c = s*32+8g+2t
    u32x4 fB[2];
    {
      const float* fbase = feats + (size_t)(b * 64) * CSTRIDE + npos * 16 + q;
#pragma unroll
      for (int s = 0; s < 2; s++) {
#pragma unroll
        for (int t2 = 0; t2 < 4; t2++) {
          int c0 = s * 32 + 8 * g + 2 * t2;
          float v0 = fbase[c0 * CSTRIDE];
          float v1 = fbase[c0 * CSTRIDE + CSTRIDE];
          fB[s][t2] = cvt_pk(v0, v1);
        }
      }
    }

    // ---- PP^T A-frag (row k=q, K-elem = ppf channel, zero beyond 8)
    u32x4 ppA = {0u, 0u, 0u, 0u};
    if (g == 0) {
      const float* pbase = ppfs + (size_t)(b * 8) * CSTRIDE + npos * 16 + q;
      float pv[8];
#pragma unroll
      for (int j = 0; j < 8; j++) pv[j] = pbase[j * CSTRIDE];
#pragma unroll
      for (int t2 = 0; t2 < 4; t2++) ppA[t2] = cvt_pk(pv[2 * t2], pv[2 * t2 + 1]);
    }

    // ---- Phase A: XN = relu(W0 @ F + b0), 16 MFMAs, D layout (rows o, cols k)
    f32x4 xnD[8];
#pragma unroll
    for (int mt = 0; mt < 8; mt++) {
      f32x4 acc = b0f[mt];
#pragma unroll
      for (int s = 0; s < 2; s++) {
        u32x4 aw = *(const u32x4*)&sT[OFF_AW0 + ((mt * 2 + s) * 64 + lane) * 4 + zoff];
        acc = mfma16(aw, fB[s], acc);
      }
      xnD[mt] = relu4(acc);
    }

    // identity column (fp32, exact) for phase J
    if (q == 0) {
#pragma unroll
      for (int mt = 0; mt < 8; mt++) *(f32x4*)(idp + mt * 16 + 4 * g) = xnD[mt];
    }

    // ---- XN D-layout -> A-frag of XN^T (cvt_pk pairs + bpermute regather)
    u32x4 XNB[4];
#pragma unroll
    for (int s = 0; s < 4; s++) {
      uint32 dA0 = cvt_pk(xnD[2 * s][0], xnD[2 * s][1]);
      uint32 dA1 = cvt_pk(xnD[2 * s][2], xnD[2 * s][3]);
      uint32 dB0 = cvt_pk(xnD[2 * s + 1][0], xnD[2 * s + 1][1]);
      uint32 dB1 = cvt_pk(xnD[2 * s + 1][2], xnD[2 * s + 1][3]);
      uint32 pa, pb;
      pa = bperm(addrLo, dA0); pb = bperm(addrLo, dB0); XNB[s][0] = isLo ? pa : pb;
      pa = bperm(addrLo, dA1); pb = bperm(addrLo, dB1); XNB[s][1] = isLo ? pa : pb;
      pa = bperm(addrHi, dA0); pb = bperm(addrHi, dB0); XNB[s][2] = isLo ? pa : pb;
      pa = bperm(addrHi, dA1); pb = bperm(addrHi, dB1); XNB[s][3] = isLo ? pa : pb;
    }

    // ---- XN[:,0] broadcast fragment (for folded x1 GEMV)
    u32x4 xc0[4];
#pragma unroll
    for (int s = 0; s < 4; s++) {
#pragma unroll
      for (int r = 0; r < 4; r++) xc0[s][r] = bperm(addrC0, XNB[s][r]);
    }

    // ---- ptf path: t^T = relu(PP^T @ pw1^T); ptf^T = t^T @ pw2^T
    f32x4 tD[4];
#pragma unroll
    for (int nt = 0; nt < 4; nt++) {
      f32x4 z = {0.f, 0.f, 0.f, 0.f};
      u32x4 bw = *(const u32x4*)&sT[OFF_PW1 + (nt * 64 + lane) * 4 + zoff];
      tD[nt] = relu4(mfma16(ppA, bw, z));
    }
    u32x4 tA[2];
#pragma unroll
    for (int s = 0; s < 2; s++) {
      uint32 dA0 = cvt_pk(tD[2 * s][0], tD[2 * s][1]);
      uint32 dA1 = cvt_pk(tD[2 * s][2], tD[2 * s][3]);
      uint32 dB0 = cvt_pk(tD[2 * s + 1][0], tD[2 * s + 1][1]);
      uint32 dB1 = cvt_pk(tD[2 * s + 1][2], tD[2 * s + 1][3]);
      uint32 pa, pb;
      pa = bperm(addrLo, dA0); pb = bperm(addrLo, dB0); tA[s][0] = isLo ? pa : pb;
      pa = bperm(addrLo, dA1); pb = bperm(addrLo, dB1); tA[s][1] = isLo ? pa : pb;
      pa = bperm(addrHi, dA0); pb = bperm(addrHi, dB0); tA[s][2] = isLo ? pa : pb;
      pa = bperm(addrHi, dA1); pb = bperm(addrHi, dB1); tA[s][3] = isLo ? pa : pb;
    }
    f32x4 ptfD[4];
#pragma unroll
    for (int nt = 0; nt < 4; nt++) {
      f32x4 acc = {0.f, 0.f, 0.f, 0.f};
#pragma unroll
      for (int s = 0; s < 2; s++) {
        u32x4 bw = *(const u32x4*)&sT[OFF_PW2 + ((nt * 2 + s) * 64 + lane) * 4 + zoff];
        acc = mfma16(tA[s], bw, acc);
      }
      ptfD[nt] = acc;
    }

    // ---- Phases C+D fused (transposed): xfs^T = XN^T@(W1^T on col0 - W2^T) + (b1-b2) + ptf
    //                                     x3^T  = XN^T@W3^T + b3 + ptf
    f32x4 xfs[4], x3v[4];
#pragma unroll
    for (int nt = 0; nt < 4; nt++) {
      f32x4 acc = {bfsF[nt], bfsF[nt], bfsF[nt], bfsF[nt]};
#pragma unroll
      for (int s = 0; s < 4; s++) {
        u32x4 bw = *(const u32x4*)&sT[OFF_W2N + ((nt * 4 + s) * 64 + lane) * 4 + zoff];
        acc = mfma16(XNB[s], bw, acc);
      }
#pragma unroll
      for (int s = 0; s < 4; s++) {
        u32x4 bw = gw1_4[(nt * 4 + s) * 64 + lane];
        acc = mfma16(xc0[s], bw, acc);
      }
      xfs[nt] = acc + ptfD[nt];

      f32x4 acc3 = {b3F[nt], b3F[nt], b3F[nt], b3F[nt]};
#pragma unroll
      for (int s = 0; s < 4; s++) {
        u32x4 bw = *(const u32x4*)&sT[OFF_W3 + ((nt * 4 + s) * 64 + lane) * 4 + zoff];
        acc3 = mfma16(XNB[s], bw, acc3);
      }
      x3v[nt] = acc3 + ptfD[nt];
    }

    // ---- Phase F: h[j] = relu(sum_{c,k} cw1[j][c*16+k] * xfs[c][k]), xfs kept fp32
    float hp[8];
#pragma unroll
    for (int j = 0; j < 8; j++) {
      float acc = 0.f;
#pragma unroll
      for (int h = 0; h < 2; h++) {
        u32x4 cwv = gcw1_4[(j * 2 + h) * 64 + lane];
#pragma unroll
        for (int rr = 0; rr < 4; rr++) {
          const int d = h * 4 + rr;
          const int nt = d >> 1;
          const int rb = (2 * d) & 3;
          acc = fmaf(bf_lo(cwv[rr]), xfs[nt][rb], acc);
          acc = fmaf(bf_hi(cwv[rr]), xfs[nt][rb + 1], acc);
        }
      }
      hp[j] = acc;
    }
#pragma unroll
    for (int j = 0; j < 8; j++) {
      float v = hp[j];
#pragma unroll
      for (int s = 1; s < 64; s <<= 1) v += __shfl_xor(v, s, 64);
      hp[j] = fmaxf(v, 0.f);
    }

    // ---- Phase G: wl = cb2 + cw2 @ h
    float wlA = cb2A, wlB = cb2B;
#pragma unroll
    for (int j = 0; j < 8; j++) {
      uint32 wp = gcw2p[j * 64 + lane];
      wlA = fmaf(bf_lo(wp), hp[j], wlA);
      wlB = fmaf(bf_hi(wp), hp[j], wlB);
    }

    // ---- Phase H: softmax over k within 16-lane groups
    float mA = wlA, mB = wlB;
#pragma unroll
    for (int s = 1; s < 16; s <<= 1) {
      mA = fmaxf(mA, __shfl_xor(mA, s, 64));
      mB = fmaxf(mB, __shfl_xor(mB, s, 64));
    }
    float eA = __expf(wlA - mA), eB = __expf(wlB - mB);
    float sA = eA, sB = eB;
#pragma unroll
    for (int s = 1; s < 16; s <<= 1) {
      sA += __shfl_xor(sA, s, 64);
      sB += __shfl_xor(sB, s, 64);
    }
    float smA = eA / sA, smB = eB / sB;

    // ---- Phase I: om[c] = relu(sum_k sm[(c&7)][k] * x3[c][k]); k = 4g+r
    float wI[4];
#pragma unroll
    for (int r = 0; r < 4; r++) {
      float wa = bpermf(addrI0 + 4 * r, smA);
      float wb = bpermf(addrI0 + 4 * r, smB);
      wI[r] = qlo ? wa : wb;
    }
    float om[4];
#pragma unroll
    for (int nt = 0; nt < 4; nt++) {
      float acc_o = 0.f;
#pragma unroll
      for (int r = 0; r < 4; r++) acc_o = fmaf(wI[r], x3v[nt][r], acc_o);
      acc_o += __shfl_xor(acc_o, 16, 64);
      acc_o += __shfl_xor(acc_o, 32, 64);
      om[nt] = fmaxf(acc_o, 0.f);
    }

    // ---- Phase J: out[o] = bout[o] + identity[o] + sum_c wout[o][c] om[c]
    float outA = boutA + idp[lane];
    float outB = boutB + idp[lane + 64];
#pragma unroll
    for (int c = 0; c < 64; c++) {
      uint32 wp = gwoutp[c * 64 + lane];
      float sv = bcast(om[c >> 4], c & 15);
      outA = fmaf(bf_lo(wp), sv, outA);
      outB = fmaf(bf_hi(wp), sv, outB);
    }
    out[(size_t)(b * 128 + lane) * 16384 + npos] = outA;
    out[(size_t)(b * 128 + lane + 64) * 16384 + npos] = outB;
  }
}

extern "C" void kernel_launch(void* const* d_in, const int* in_sizes, int n_in,
                              void* d_out, int out_size, void* d_ws, size_t ws_size,
                              hipStream_t stream) {
  const float* feats = (const float*)d_in[0];
  const float* ppfs = (const float*)d_in[1];
  const float* w0 = (const float*)d_in[2];
  const float* b0 = (const float*)d_in[3];
  const float* w1 = (const float*)d_in[4];
  const float* b1 = (const float*)d_in[5];
  const float* w2 = (const float*)d_in[6];
  const float* b2 = (const float*)d_in[7];
  const float* w3 = (const float*)d_in[8];
  const float* b3 = (const float*)d_in[9];
  const float* pw1 = (const float*)d_in[10];
  const float* pw2 = (const float*)d_in[11];
  const float* cw1 = (const float*)d_in[12];
  const float* cw2 = (const float*)d_in[13];
  const float* cb2 = (const float*)d_in[14];
  const float* wout = (const float*)d_in[15];
  const float* bout = (const float*)d_in[16];
  (void)in_sizes; (void)n_in; (void)out_size; (void)ws_size;

  uint32* ws = (uint32*)d_ws;

  hipLaunchKernelGGL(pack_weights_kernel, dim3(8), dim3(256), 0, stream,
                     w0, w1, w2, w3, pw1, pw2, cw1, cw2, wout, ws);
  hipLaunchKernelGGL(pt_mfma, dim3(NBLOCKS), dim3(256), 0, stream,
                     feats, ppfs, b0, b1, b2, b3, cb2, bout, ws, (float*)d_out);
}